// Round 1
// baseline (175437.329 us; speedup 1.0000x reference)
//
#include <hip/hip_runtime.h>
#include <math.h>

// Problem constants
#define B_BATCH 64
#define T_STEPS 256
#define C_COMP  64
#define H_DIM   64
#define HB_DIM  128
#define HP 68     // padded row stride for [64][64] LDS tiles (16B-aligned rows, <=2-way bank conflict)
#define BP 132    // padded row stride for [64][128] LDS tiles

// output offsets (floats)
#define MAT_OFF  128
#define TL_OFF   67108992
#define PRED_OFF 67141760
#define XC_OFF   68186240

__device__ __forceinline__ float sigm(float v) { return 1.0f / (1.0f + expf(-v)); }

// ---------------- precompute: gi = x * avec + cvec (rank-1 embedding+input path) ------------
__global__ void precompute_kernel(const float* __restrict__ w_ih,
                                  const float* __restrict__ embed_w,
                                  const float* __restrict__ embed_b,
                                  const float* __restrict__ b_ih,
                                  float* __restrict__ avec,
                                  float* __restrict__ cvec)
{
    int g = threadIdx.x;
    if (g < 192) {
        float a = 0.f, c = 0.f;
        for (int e = 0; e < 32; ++e) {
            float w = w_ih[g * 32 + e];
            a += w * embed_w[e];
            c += w * embed_b[e];
        }
        avec[g] = a;
        cvec[g] = c + b_ih[g];
    }
}

// ---------------- one MLP layer inside the scan block ------------------------------------
// 256 threads; thread (c = tid>>2, sub = tid&3) computes out[c][sub*32 .. sub*32+31].
template<int K, bool RELU>
__device__ __forceinline__ void mlp_layer(const float* in, int instride,
                                          const float* __restrict__ W,
                                          const float* __restrict__ bias,
                                          float* out, int outstride, int c, int sub)
{
    float acc[32];
#pragma unroll
    for (int i = 0; i < 32; ++i) acc[i] = bias[sub * 32 + i];
#pragma unroll 2
    for (int p4 = 0; p4 < K / 4; ++p4) {
        float4 hv = *reinterpret_cast<const float4*>(&in[c * instride + p4 * 4]);
#pragma unroll
        for (int i = 0; i < 32; ++i) {
            float4 wv = *reinterpret_cast<const float4*>(&W[(size_t)(sub * 32 + i) * K + p4 * 4]);
            acc[i] = fmaf(hv.x, wv.x, fmaf(hv.y, wv.y, fmaf(hv.z, wv.z, fmaf(hv.w, wv.w, acc[i]))));
        }
    }
#pragma unroll
    for (int i = 0; i < 32; ++i) {
        float v = acc[i];
        if (RELU) v = fmaxf(v, 0.f);
        out[c * outstride + sub * 32 + i] = v;
    }
    __syncthreads();
}

// ---------------- the sequential scan: one block per batch -------------------------------
__global__ __launch_bounds__(256) void scan_kernel(
    const float* __restrict__ x,
    const float* __restrict__ w_hh, const float* __restrict__ b_hh,
    const float* __restrict__ avec, const float* __restrict__ cvec,
    const float* __restrict__ q1w, const float* __restrict__ q1b,
    const float* __restrict__ q2w, const float* __restrict__ q2b,
    const float* __restrict__ q3w, const float* __restrict__ q3b,
    const float* __restrict__ k1w, const float* __restrict__ k1b,
    const float* __restrict__ k2w, const float* __restrict__ k2b,
    const float* __restrict__ k3w, const float* __restrict__ k3b,
    const float* __restrict__ gate_bias,
    const float* __restrict__ pred_w, const float* __restrict__ pred_b,
    float* __restrict__ matrices, float* __restrict__ predicted)
{
    __shared__ __align__(16) float hg[C_COMP * HP];     // current hidden state [64][68]
    __shared__ __align__(16) float bufX[C_COMP * BP];   // ping  [64][132]
    __shared__ __align__(16) float bufY[C_COMP * BP];   // pong
    __shared__ __align__(16) float Qf[C_COMP * BP];     // q MLP output
    __shared__ __align__(16) float Kf[C_COMP * BP];     // k MLP output
    __shared__ float red[4];

    const int tid = threadIdx.x;
    const int b   = blockIdx.x;
    const int c   = tid >> 2;
    const int sub = tid & 3;

    for (int i = tid; i < C_COMP * HP; i += 256) hg[i] = 0.f;
    __syncthreads();

    const float predb = pred_b[0];

    for (int t = 0; t < T_STEPS; ++t) {
        const float xv = x[((size_t)b * T_STEPS + t) * C_COMP + c];

        // ================= GRU cell =================
        // cache own h row in registers (compile-time indexed only)
        float hrow[H_DIM];
#pragma unroll
        for (int p4 = 0; p4 < H_DIM / 4; ++p4) {
            float4 hv = *reinterpret_cast<const float4*>(&hg[c * HP + p4 * 4]);
            hrow[p4 * 4 + 0] = hv.x; hrow[p4 * 4 + 1] = hv.y;
            hrow[p4 * 4 + 2] = hv.z; hrow[p4 * 4 + 3] = hv.w;
        }
        float hnew[16];
        for (int jj = 0; jj < 16; ++jj) {
            const int j = sub * 16 + jj;
            float dr = 0.f, dz = 0.f, dn = 0.f;
            const float4* wr = reinterpret_cast<const float4*>(&w_hh[(size_t)j * H_DIM]);
            const float4* wz = reinterpret_cast<const float4*>(&w_hh[(size_t)(64 + j) * H_DIM]);
            const float4* wn = reinterpret_cast<const float4*>(&w_hh[(size_t)(128 + j) * H_DIM]);
#pragma unroll
            for (int p4 = 0; p4 < 16; ++p4) {
                float4 wv = wr[p4];
                dr = fmaf(hrow[p4*4+0], wv.x, fmaf(hrow[p4*4+1], wv.y, fmaf(hrow[p4*4+2], wv.z, fmaf(hrow[p4*4+3], wv.w, dr))));
                float4 wv2 = wz[p4];
                dz = fmaf(hrow[p4*4+0], wv2.x, fmaf(hrow[p4*4+1], wv2.y, fmaf(hrow[p4*4+2], wv2.z, fmaf(hrow[p4*4+3], wv2.w, dz))));
                float4 wv3 = wn[p4];
                dn = fmaf(hrow[p4*4+0], wv3.x, fmaf(hrow[p4*4+1], wv3.y, fmaf(hrow[p4*4+2], wv3.z, fmaf(hrow[p4*4+3], wv3.w, dn))));
            }
            const float gr = dr + b_hh[j];
            const float gz = dz + b_hh[64 + j];
            const float gn = dn + b_hh[128 + j];
            const float ir = fmaf(xv, avec[j],        cvec[j]);
            const float iz = fmaf(xv, avec[64 + j],   cvec[64 + j]);
            const float in_ = fmaf(xv, avec[128 + j], cvec[128 + j]);
            const float r = sigm(ir + gr);
            const float z = sigm(iz + gz);
            const float n = tanhf(fmaf(r, gn, in_));
            const float hold = hg[c * HP + j];          // LDS read (runtime j; avoid reg-array scratch)
            hnew[jj] = fmaf(z, hold - n, n);            // (1-z)*n + z*h
        }
        __syncthreads();
#pragma unroll
        for (int jj = 0; jj < 16; ++jj) hg[c * HP + sub * 16 + jj] = hnew[jj];
        __syncthreads();

        // ================= BTP: q and k MLPs =================
        mlp_layer<64,  true >(hg,   HP, q1w, q1b, bufX, BP, c, sub);
        mlp_layer<128, true >(bufX, BP, q2w, q2b, bufY, BP, c, sub);
        mlp_layer<128, false>(bufY, BP, q3w, q3b, Qf,   BP, c, sub);
        mlp_layer<64,  true >(hg,   HP, k1w, k1b, bufX, BP, c, sub);
        mlp_layer<128, true >(bufX, BP, k2w, k2b, bufY, BP, c, sub);
        mlp_layer<128, false>(bufY, BP, k3w, k3b, Kf,   BP, c, sub);

        // ================= transfer = q @ k.T =================
        float tacc[16];
#pragma unroll
        for (int jj = 0; jj < 16; ++jj) tacc[jj] = 0.f;
        for (int p4 = 0; p4 < HB_DIM / 4; ++p4) {
            float4 qv = *reinterpret_cast<const float4*>(&Qf[c * BP + p4 * 4]);
#pragma unroll
            for (int jj = 0; jj < 16; ++jj) {
                float4 kv = *reinterpret_cast<const float4*>(&Kf[(sub * 16 + jj) * BP + p4 * 4]);
                tacc[jj] = fmaf(qv.x, kv.x, fmaf(qv.y, kv.y, fmaf(qv.z, kv.z, fmaf(qv.w, kv.w, tacc[jj]))));
            }
        }
        float ss = 0.f;
#pragma unroll
        for (int jj = 0; jj < 16; ++jj) {
            bufX[c * BP + sub * 16 + jj] = tacc[jj];
            ss = fmaf(tacc[jj], tacc[jj], ss);
        }
        // block-wide sum of squares
        for (int off = 32; off; off >>= 1) ss += __shfl_xor(ss, off);
        if ((tid & 63) == 0) red[tid >> 6] = ss;
        __syncthreads();
        const float nrm = sqrtf(red[0] + red[1] + red[2] + red[3]);
        const float inv = 1.0f / nrm;

        // ================= normalize, gate, write matrices =================
        const size_t mbase = ((size_t)b * T_STEPS + t) * (C_COMP * C_COMP);
        for (int it = 0; it < 16; ++it) {
            const int e  = it * 256 + tid;      // linear -> coalesced global writes
            const int ci = e >> 6, cj = e & 63;
            const float tv = bufX[ci * BP + cj] * inv;
            const float g  = sigm(fabsf(tv) + gate_bias[e]);
            const float val = tv * g;
            matrices[mbase + e] = val;
            bufX[ci * BP + cj] = val;           // in-place: each element owned by one thread
        }
        __syncthreads();

        // ================= h = transfer @ h =================
        float4 hacc0 = {0,0,0,0}, hacc1 = {0,0,0,0}, hacc2 = {0,0,0,0}, hacc3 = {0,0,0,0};
        for (int cj = 0; cj < C_COMP; ++cj) {
            const float tv = bufX[c * BP + cj];
            float4 h0 = *reinterpret_cast<const float4*>(&hg[cj * HP + sub * 16 + 0]);
            float4 h1 = *reinterpret_cast<const float4*>(&hg[cj * HP + sub * 16 + 4]);
            float4 h2 = *reinterpret_cast<const float4*>(&hg[cj * HP + sub * 16 + 8]);
            float4 h3 = *reinterpret_cast<const float4*>(&hg[cj * HP + sub * 16 + 12]);
            hacc0.x = fmaf(tv, h0.x, hacc0.x); hacc0.y = fmaf(tv, h0.y, hacc0.y);
            hacc0.z = fmaf(tv, h0.z, hacc0.z); hacc0.w = fmaf(tv, h0.w, hacc0.w);
            hacc1.x = fmaf(tv, h1.x, hacc1.x); hacc1.y = fmaf(tv, h1.y, hacc1.y);
            hacc1.z = fmaf(tv, h1.z, hacc1.z); hacc1.w = fmaf(tv, h1.w, hacc1.w);
            hacc2.x = fmaf(tv, h2.x, hacc2.x); hacc2.y = fmaf(tv, h2.y, hacc2.y);
            hacc2.z = fmaf(tv, h2.z, hacc2.z); hacc2.w = fmaf(tv, h2.w, hacc2.w);
            hacc3.x = fmaf(tv, h3.x, hacc3.x); hacc3.y = fmaf(tv, h3.y, hacc3.y);
            hacc3.z = fmaf(tv, h3.z, hacc3.z); hacc3.w = fmaf(tv, h3.w, hacc3.w);
        }
        __syncthreads();
        *reinterpret_cast<float4*>(&hg[c * HP + sub * 16 + 0])  = hacc0;
        *reinterpret_cast<float4*>(&hg[c * HP + sub * 16 + 4])  = hacc1;
        *reinterpret_cast<float4*>(&hg[c * HP + sub * 16 + 8])  = hacc2;
        *reinterpret_cast<float4*>(&hg[c * HP + sub * 16 + 12]) = hacc3;
        __syncthreads();

        // ================= predictor (uses post-BTP h, t = 0..T-2) =================
        if (t < T_STEPS - 1 && tid < C_COMP) {
            float acc = predb;
            for (int j = 0; j < H_DIM; ++j) acc = fmaf(hg[tid * HP + j], pred_w[j], acc);
            predicted[((size_t)b * (T_STEPS - 1) + t) * C_COMP + tid] = acc;
        }
        // next iteration's GRU reads hg before its first barrier, so no extra sync needed
    }
}

// ---------------- copy x[:,1:,:] ----------------------------------------------------------
__global__ void copyx_kernel(const float* __restrict__ x, float* __restrict__ out5)
{
    int i = blockIdx.x * 256 + threadIdx.x;
    if (i < B_BATCH * (T_STEPS - 1) * C_COMP) {
        int b = i / ((T_STEPS - 1) * C_COMP);
        int r = i - b * (T_STEPS - 1) * C_COMP;
        out5[i] = x[(size_t)b * (T_STEPS * C_COMP) + r + C_COMP];
    }
}

// ---------------- fp32 tiled GEMM: C = act(A[M,K] @ B[N,K]^T + bias) ----------------------
__global__ __launch_bounds__(256) void gemm_bias_act(
    const float* __restrict__ A, const float* __restrict__ Bw,
    const float* __restrict__ bias, float* __restrict__ Cout,
    int M, int N, int K, int relu)
{
    __shared__ __align__(16) float As[16 * 132];
    __shared__ __align__(16) float Bs[16 * 132];
    const int tid = threadIdx.x;
    const int m0 = blockIdx.x * 128, n0 = blockIdx.y * 128;
    const int tr = tid >> 4, tc = tid & 15;
    const int lrow = tid >> 1;
    const int lk = (tid & 1) * 8;

    float acc[8][8];
#pragma unroll
    for (int i = 0; i < 8; ++i)
#pragma unroll
        for (int j = 0; j < 8; ++j) acc[i][j] = 0.f;

    for (int k0 = 0; k0 < K; k0 += 16) {
        float4 a0 = *reinterpret_cast<const float4*>(&A[(size_t)(m0 + lrow) * K + k0 + lk]);
        float4 a1 = *reinterpret_cast<const float4*>(&A[(size_t)(m0 + lrow) * K + k0 + lk + 4]);
        float4 b0 = *reinterpret_cast<const float4*>(&Bw[(size_t)(n0 + lrow) * K + k0 + lk]);
        float4 b1 = *reinterpret_cast<const float4*>(&Bw[(size_t)(n0 + lrow) * K + k0 + lk + 4]);
        __syncthreads();
        As[(lk + 0) * 132 + lrow] = a0.x; As[(lk + 1) * 132 + lrow] = a0.y;
        As[(lk + 2) * 132 + lrow] = a0.z; As[(lk + 3) * 132 + lrow] = a0.w;
        As[(lk + 4) * 132 + lrow] = a1.x; As[(lk + 5) * 132 + lrow] = a1.y;
        As[(lk + 6) * 132 + lrow] = a1.z; As[(lk + 7) * 132 + lrow] = a1.w;
        Bs[(lk + 0) * 132 + lrow] = b0.x; Bs[(lk + 1) * 132 + lrow] = b0.y;
        Bs[(lk + 2) * 132 + lrow] = b0.z; Bs[(lk + 3) * 132 + lrow] = b0.w;
        Bs[(lk + 4) * 132 + lrow] = b1.x; Bs[(lk + 5) * 132 + lrow] = b1.y;
        Bs[(lk + 6) * 132 + lrow] = b1.z; Bs[(lk + 7) * 132 + lrow] = b1.w;
        __syncthreads();
#pragma unroll
        for (int kk = 0; kk < 16; ++kk) {
            float av[8], bv[8];
            float4 t0 = *reinterpret_cast<const float4*>(&As[kk * 132 + tr * 8]);
            float4 t1 = *reinterpret_cast<const float4*>(&As[kk * 132 + tr * 8 + 4]);
            av[0]=t0.x; av[1]=t0.y; av[2]=t0.z; av[3]=t0.w; av[4]=t1.x; av[5]=t1.y; av[6]=t1.z; av[7]=t1.w;
            float4 u0 = *reinterpret_cast<const float4*>(&Bs[kk * 132 + tc * 8]);
            float4 u1 = *reinterpret_cast<const float4*>(&Bs[kk * 132 + tc * 8 + 4]);
            bv[0]=u0.x; bv[1]=u0.y; bv[2]=u0.z; bv[3]=u0.w; bv[4]=u1.x; bv[5]=u1.y; bv[6]=u1.z; bv[7]=u1.w;
#pragma unroll
            for (int i = 0; i < 8; ++i)
#pragma unroll
                for (int j = 0; j < 8; ++j) acc[i][j] = fmaf(av[i], bv[j], acc[i][j]);
        }
    }
#pragma unroll
    for (int i = 0; i < 8; ++i) {
        const int cm = m0 + tr * 8 + i;
#pragma unroll
        for (int j = 0; j < 8; ++j) {
            const int cn = n0 + tc * 8 + j;
            float v = acc[i][j] + bias[cn];
            if (relu) v = fmaxf(v, 0.f);
            Cout[(size_t)cm * N + cn] = v;
        }
    }
}

// ---------------- classifier layer 3: [M,1024] -> time_logits [M,2] -----------------------
__global__ __launch_bounds__(256) void clf3_kernel(const float* __restrict__ h2,
    const float* __restrict__ w3, const float* __restrict__ b3,
    float* __restrict__ TL, int m0, int Mchunk)
{
    const int lane = threadIdx.x & 63;
    const int w = threadIdx.x >> 6;
    const int r = blockIdx.x * 4 + w;
    if (r >= Mchunk) return;
    const float* hr = h2 + (size_t)r * 1024;
    float a0 = 0.f, a1 = 0.f;
    for (int i = 0; i < 16; ++i) {
        const int k = lane + i * 64;
        const float hv = hr[k];
        a0 = fmaf(hv, w3[k], a0);
        a1 = fmaf(hv, w3[1024 + k], a1);
    }
    for (int off = 32; off; off >>= 1) { a0 += __shfl_xor(a0, off); a1 += __shfl_xor(a1, off); }
    if (lane == 0) {
        const size_t row = (size_t)m0 + r;
        TL[row * 2 + 0] = a0 + b3[0];
        TL[row * 2 + 1] = a1 + b3[1];
    }
}

// ---------------- logits = mean over T of time_logits -------------------------------------
__global__ void logits_kernel(const float* __restrict__ TL, float* __restrict__ out)
{
    const int tid = threadIdx.x;
    if (tid >= 128) return;
    const int b = tid >> 1, o = tid & 1;
    float s = 0.f;
    for (int t = 0; t < T_STEPS; ++t) s += TL[((size_t)b * T_STEPS + t) * 2 + o];
    out[b * 2 + o] = s * (1.0f / 256.0f);
}

extern "C" void kernel_launch(void* const* d_in, const int* in_sizes, int n_in,
                              void* d_out, int out_size, void* d_ws, size_t ws_size,
                              hipStream_t stream)
{
    const float* x       = (const float*)d_in[0];
    const float* embed_w = (const float*)d_in[1];
    const float* embed_b = (const float*)d_in[2];
    const float* w_ih    = (const float*)d_in[3];
    const float* w_hh    = (const float*)d_in[4];
    const float* b_ih    = (const float*)d_in[5];
    const float* b_hh    = (const float*)d_in[6];
    const float* q1w = (const float*)d_in[7],  *q1b = (const float*)d_in[8];
    const float* q2w = (const float*)d_in[9],  *q2b = (const float*)d_in[10];
    const float* q3w = (const float*)d_in[11], *q3b = (const float*)d_in[12];
    const float* k1w = (const float*)d_in[13], *k1b = (const float*)d_in[14];
    const float* k2w = (const float*)d_in[15], *k2b = (const float*)d_in[16];
    const float* k3w = (const float*)d_in[17], *k3b = (const float*)d_in[18];
    const float* gate_bias = (const float*)d_in[19];
    const float* c1w = (const float*)d_in[20], *c1b = (const float*)d_in[21];
    const float* c2w = (const float*)d_in[22], *c2b = (const float*)d_in[23];
    const float* c3w = (const float*)d_in[24], *c3b = (const float*)d_in[25];
    const float* pw  = (const float*)d_in[26], *pb  = (const float*)d_in[27];

    float* out       = (float*)d_out;
    float* logits    = out;
    float* matrices  = out + MAT_OFF;
    float* TL        = out + TL_OFF;
    float* predicted = out + PRED_OFF;
    float* xcopy     = out + XC_OFF;

    float* ws   = (float*)d_ws;
    float* avec = ws;
    float* cvec = ws + 192;
    float* h1   = ws + 512;

    // adaptive classifier chunk size (rows), power of two dividing 16384
    size_t avail = (ws_size / 4 > 512) ? ws_size / 4 - 512 : 0;
    int R = 16384;
    while (R > 128 && (size_t)R * 3072 > avail) R >>= 1;
    float* h2 = h1 + (size_t)R * 2048;

    precompute_kernel<<<1, 256, 0, stream>>>(w_ih, embed_w, embed_b, b_ih, avec, cvec);

    scan_kernel<<<B_BATCH, 256, 0, stream>>>(x, w_hh, b_hh, avec, cvec,
        q1w, q1b, q2w, q2b, q3w, q3b, k1w, k1b, k2w, k2b, k3w, k3b,
        gate_bias, pw, pb, matrices, predicted);

    copyx_kernel<<<(B_BATCH * (T_STEPS - 1) * C_COMP + 255) / 256, 256, 0, stream>>>(x, xcopy);

    const int Mtot = B_BATCH * T_STEPS;   // 16384
    for (int m0 = 0; m0 < Mtot; m0 += R) {
        gemm_bias_act<<<dim3(R / 128, 2048 / 128), 256, 0, stream>>>(
            matrices + (size_t)m0 * 4096, c1w, c1b, h1, R, 2048, 4096, 1);
        gemm_bias_act<<<dim3(R / 128, 1024 / 128), 256, 0, stream>>>(
            h1, c2w, c2b, h2, R, 1024, 2048, 1);
        clf3_kernel<<<R / 4, 256, 0, stream>>>(h2, c3w, c3b, TL, m0, R);
    }
    logits_kernel<<<1, 128, 0, stream>>>(TL, logits);
}

// Round 2
// 6893.239 us; speedup vs baseline: 25.4506x; 25.4506x over previous
//
#include <hip/hip_runtime.h>
#include <math.h>

#define B_BATCH 64
#define T_STEPS 256
#define C_COMP  64

// ws layout: floats [0..191] avec, [192..383] cvec; byte 2048+ : bf16 weights
#define WSW_BYTE_OFF 2048
#define WHH_OFF 0
#define Q1_OFF 12288
#define K1_OFF 20480
#define Q2_OFF 28672
#define K2_OFF 45056
#define Q3_OFF 61440
#define K3_OFF 77824
#define WTOT 94208
#define CLF_F32_OFF 47616   // 512 + WTOT/2 floats

// output offsets (floats)
#define MAT_OFF  128
#define TL_OFF   67108992
#define PRED_OFF 67141760
#define XC_OFF   68186240

typedef __attribute__((ext_vector_type(8))) short short8;
typedef __attribute__((ext_vector_type(4))) float f32x4;
#define MFMA16(a,b,c) __builtin_amdgcn_mfma_f32_16x16x32_bf16(a,b,c,0,0,0)

__device__ __forceinline__ float sigm(float v) { return 1.0f / (1.0f + expf(-v)); }
__device__ __forceinline__ float tanh_f(float v) {
    float e = expf(2.0f * v);              // inf-safe: tanh(big)=1, tanh(-big)=-1
    return 1.0f - 2.0f / (e + 1.0f);
}
__device__ __forceinline__ short f2bf(float f) {  // RNE f32->bf16 bits
    unsigned u = __float_as_uint(f);
    u += 0x7fffu + ((u >> 16) & 1u);
    return (short)(u >> 16);
}

// ---------------- precompute rank-1 embedding+input path --------------------------------
__global__ void precompute_kernel(const float* __restrict__ w_ih,
                                  const float* __restrict__ embed_w,
                                  const float* __restrict__ embed_b,
                                  const float* __restrict__ b_ih,
                                  float* __restrict__ avec, float* __restrict__ cvec)
{
    int g = threadIdx.x;
    if (g < 192) {
        float a = 0.f, c = 0.f;
        for (int e = 0; e < 32; ++e) {
            float w = w_ih[g * 32 + e];
            a += w * embed_w[e];
            c += w * embed_b[e];
        }
        avec[g] = a;
        cvec[g] = c + b_ih[g];
    }
}

__global__ void tobf16_kernel(const float* __restrict__ src, short* __restrict__ dst, int n)
{
    int i = blockIdx.x * 256 + threadIdx.x;
    if (i < n) dst[i] = f2bf(src[i]);
}

// one MLP layer: this wave computes 2 column-strips (s0,s1) of out[64][*], all 4 m-tiles.
template<int KST, bool RELU>
__device__ __forceinline__ void two_strip_layer(
    const short* __restrict__ A, const int ast,
    const short8* __restrict__ Bs0, const short8* __restrict__ Bs1,
    const float bias0, const float bias1,
    short* __restrict__ outb, const int ost,
    const int s0, const int s1, const int ln, const int lh)
{
    f32x4 acc0[4], acc1[4];
#pragma unroll
    for (int m = 0; m < 4; ++m) {
        acc0[m] = (f32x4){bias0, bias0, bias0, bias0};
        acc1[m] = (f32x4){bias1, bias1, bias1, bias1};
    }
#pragma unroll
    for (int kk = 0; kk < KST; ++kk) {
#pragma unroll
        for (int m = 0; m < 4; ++m) {
            short8 a = *(const short8*)&A[(m * 16 + ln) * ast + kk * 32 + lh * 8];
            acc0[m] = MFMA16(a, Bs0[kk], acc0[m]);
            acc1[m] = MFMA16(a, Bs1[kk], acc1[m]);
        }
    }
#pragma unroll
    for (int m = 0; m < 4; ++m) {
#pragma unroll
        for (int q = 0; q < 4; ++q) {
            const int row = m * 16 + lh * 4 + q;
            float v0 = acc0[m][q], v1 = acc1[m][q];
            if (RELU) { v0 = fmaxf(v0, 0.f); v1 = fmaxf(v1, 0.f); }
            outb[row * ost + s0 * 16 + ln] = f2bf(v0);
            outb[row * ost + s1 * 16 + ln] = f2bf(v1);
        }
    }
}

// ---------------- the scan: one block (8 waves) per batch, MFMA everywhere ---------------
__global__ __launch_bounds__(512) void scan_kernel(
    const float* __restrict__ x, const float* __restrict__ b_hh,
    const float* __restrict__ avec, const float* __restrict__ cvec,
    const short* __restrict__ wsw,
    const float* __restrict__ q1b, const float* __restrict__ q2b, const float* __restrict__ q3b,
    const float* __restrict__ k1b, const float* __restrict__ k2b, const float* __restrict__ k3b,
    const float* __restrict__ gate_bias,
    const float* __restrict__ pred_w, const float* __restrict__ pred_b,
    float* __restrict__ matrices, float* __restrict__ predicted)
{
    __shared__ __align__(16) float h32[64 * 67];   // post-phase h, fp32, odd stride
    __shared__ __align__(16) short hb [64 * 72];   // h bf16 row-major
    __shared__ __align__(16) short hbT[64 * 72];   // post-GRU h transposed
    __shared__ __align__(16) short qf [64 * 136];
    __shared__ __align__(16) short kf [64 * 136];
    __shared__ __align__(16) char scratch[69632];  // union: gates | act1q,act1k,act2q,act2k | tf,tb
    __shared__ float avec_s[192], cvec_s[192], bhh_s[192], pw_s[64], xrow[64], red[8];

    float* gates = (float*)scratch;                 // [64][193] f32
    short* act1q = (short*)scratch;                 // [64][136] bf16
    short* act1k = (short*)(scratch + 17408);
    short* act2q = (short*)(scratch + 34816);
    short* act2k = (short*)(scratch + 52224);
    float* tf    = (float*)scratch;                 // [64][67] f32
    short* tb    = (short*)(scratch + 17408);       // [64][72] bf16

    const int tid = threadIdx.x;
    const int b = blockIdx.x;
    const int w = tid >> 6, lane = tid & 63;
    const int ln = lane & 15, lh = lane >> 4;
    const int wq = w & 3;

    for (int i = tid; i < 64 * 67; i += 512) h32[i] = 0.f;
    for (int i = tid; i < 64 * 72; i += 512) hb[i] = 0;
    if (tid < 192) { avec_s[tid] = avec[tid]; cvec_s[tid] = cvec[tid]; bhh_s[tid] = b_hh[tid]; }
    if (tid < 64) pw_s[tid] = pred_w[tid];
    const float pbv = pred_b[0];

    // ---- preload all weight B-fragments into registers (constant across all t) ----
    const short* whh_b = wsw + WHH_OFF;
    const short* l1w = (w < 4) ? wsw + Q1_OFF : wsw + K1_OFF;
    const short* l2w = (w < 4) ? wsw + Q2_OFF : wsw + K2_OFF;
    const short* l3w = (w < 4) ? wsw + Q3_OFF : wsw + K3_OFF;
    const float* l1b = (w < 4) ? q1b : k1b;
    const float* l2b = (w < 4) ? q2b : k2b;
    const float* l3b = (w < 4) ? q3b : k3b;

    short8 Bg[2][2], B1[2][2], B2[2][4], B3[2][4];
    {
        const int sg1 = (w < 4) ? (w + 8) : w;
#pragma unroll
        for (int kk = 0; kk < 2; ++kk) {
            Bg[0][kk] = *(const short8*)&whh_b[(w   * 16 + ln) * 64 + kk * 32 + lh * 8];
            Bg[1][kk] = *(const short8*)&whh_b[(sg1 * 16 + ln) * 64 + kk * 32 + lh * 8];
        }
#pragma unroll
        for (int s = 0; s < 2; ++s) {
            const int strip = wq + s * 4;
#pragma unroll
            for (int kk = 0; kk < 2; ++kk)
                B1[s][kk] = *(const short8*)&l1w[(strip * 16 + ln) * 64 + kk * 32 + lh * 8];
#pragma unroll
            for (int kk = 0; kk < 4; ++kk) {
                B2[s][kk] = *(const short8*)&l2w[(strip * 16 + ln) * 128 + kk * 32 + lh * 8];
                B3[s][kk] = *(const short8*)&l3w[(strip * 16 + ln) * 128 + kk * 32 + lh * 8];
            }
        }
    }
    const float b1v0 = l1b[wq * 16 + ln],       b1v1 = l1b[(wq + 4) * 16 + ln];
    const float b2v0 = l2b[wq * 16 + ln],       b2v1 = l2b[(wq + 4) * 16 + ln];
    const float b3v0 = l3b[wq * 16 + ln],       b3v1 = l3b[(wq + 4) * 16 + ln];
    __syncthreads();

    for (int t = 0; t < T_STEPS; ++t) {
        // ===== phase 1: gh = hb @ w_hh^T  (out [64][192] f32 in gates) =====
        {
            f32x4 a0[4], a1[4];
#pragma unroll
            for (int m = 0; m < 4; ++m) { a0[m] = (f32x4){0,0,0,0}; a1[m] = (f32x4){0,0,0,0}; }
#pragma unroll
            for (int kk = 0; kk < 2; ++kk)
#pragma unroll
                for (int m = 0; m < 4; ++m) {
                    short8 av = *(const short8*)&hb[(m * 16 + ln) * 72 + kk * 32 + lh * 8];
                    a0[m] = MFMA16(av, Bg[0][kk], a0[m]);
                    a1[m] = MFMA16(av, Bg[1][kk], a1[m]);
                }
#pragma unroll
            for (int m = 0; m < 4; ++m)
#pragma unroll
                for (int q = 0; q < 4; ++q)
                    gates[(m * 16 + lh * 4 + q) * 193 + w * 16 + ln] = a0[m][q];
            if (w < 4) {
#pragma unroll
                for (int m = 0; m < 4; ++m)
#pragma unroll
                    for (int q = 0; q < 4; ++q)
                        gates[(m * 16 + lh * 4 + q) * 193 + (w + 8) * 16 + ln] = a1[m][q];
            }
        }
        if (tid < 64) xrow[tid] = x[((size_t)b * T_STEPS + t) * 64 + tid];
        __syncthreads();

        // ===== phase 2: GRU elementwise -> h32, hb, hbT =====
        {
            const int c = tid >> 3, j0 = (tid & 7) * 8;
            const float xv = xrow[c];
#pragma unroll
            for (int jj = 0; jj < 8; ++jj) {
                const int j = j0 + jj;
                const float ghr = gates[c * 193 + j]       + bhh_s[j];
                const float ghz = gates[c * 193 + 64 + j]  + bhh_s[64 + j];
                const float ghn = gates[c * 193 + 128 + j] + bhh_s[128 + j];
                const float r = sigm(fmaf(xv, avec_s[j],        cvec_s[j])        + ghr);
                const float z = sigm(fmaf(xv, avec_s[64 + j],   cvec_s[64 + j])   + ghz);
                const float n = tanh_f(fmaf(xv, avec_s[128 + j], cvec_s[128 + j]) + r * ghn);
                const float hold = h32[c * 67 + j];
                const float hn = fmaf(z, hold - n, n);
                h32[c * 67 + j] = hn;
                const short hv = f2bf(hn);
                hb[c * 72 + j] = hv;
                hbT[j * 72 + c] = hv;
            }
        }
        __syncthreads();

        // ===== phases 3-5: q / k MLPs (waves 0-3 = q path, 4-7 = k path) =====
        short* o1 = (w < 4) ? act1q : act1k;
        two_strip_layer<2, true >(hb, 72, B1[0], B1[1], b1v0, b1v1, o1, 136, wq, wq + 4, ln, lh);
        __syncthreads();
        short* o2 = (w < 4) ? act2q : act2k;
        two_strip_layer<4, true >(o1, 136, B2[0], B2[1], b2v0, b2v1, o2, 136, wq, wq + 4, ln, lh);
        __syncthreads();
        short* o3 = (w < 4) ? qf : kf;
        two_strip_layer<4, false>(o2, 136, B3[0], B3[1], b3v0, b3v1, o3, 136, wq, wq + 4, ln, lh);
        __syncthreads();

        // ===== phase 6: transfer = qf @ kf^T  -> tf f32, sumsq -> red =====
        {
            const int m = wq, n0 = w >> 2;
            f32x4 ac0 = {0,0,0,0}, ac1 = {0,0,0,0};
#pragma unroll
            for (int kk = 0; kk < 4; ++kk) {
                short8 av = *(const short8*)&qf[(m * 16 + ln) * 136 + kk * 32 + lh * 8];
                short8 b0 = *(const short8*)&kf[(n0 * 16 + ln) * 136 + kk * 32 + lh * 8];
                short8 b1 = *(const short8*)&kf[((n0 + 2) * 16 + ln) * 136 + kk * 32 + lh * 8];
                ac0 = MFMA16(av, b0, ac0);
                ac1 = MFMA16(av, b1, ac1);
            }
            float ss = 0.f;
#pragma unroll
            for (int q = 0; q < 4; ++q) {
                const int row = m * 16 + lh * 4 + q;
                tf[row * 67 + n0 * 16 + ln] = ac0[q];
                tf[row * 67 + (n0 + 2) * 16 + ln] = ac1[q];
                ss = fmaf(ac0[q], ac0[q], fmaf(ac1[q], ac1[q], ss));
            }
#pragma unroll
            for (int off = 1; off < 64; off <<= 1) ss += __shfl_xor(ss, off);
            if (lane == 0) red[w] = ss;
        }
        __syncthreads();

        // ===== phase 7: normalize + gate -> matrices (global) + tb (bf16) =====
        {
            const float ssum = red[0]+red[1]+red[2]+red[3]+red[4]+red[5]+red[6]+red[7];
            const float inv = 1.0f / sqrtf(ssum);
            const size_t mbase = ((size_t)b * T_STEPS + t) * 4096;
#pragma unroll
            for (int it = 0; it < 8; ++it) {
                const int e = it * 512 + tid;
                const int ci = e >> 6, cj = e & 63;
                const float tv = tf[ci * 67 + cj] * inv;
                const float g = sigm(fabsf(tv) + gate_bias[e]);
                const float val = tv * g;
                matrices[mbase + e] = val;
                tb[ci * 72 + cj] = f2bf(val);
            }
        }
        __syncthreads();

        // ===== phase 8: h = tb @ h_postGRU  (B from hbT) -> h32, hb =====
        {
            const int m = wq, n0 = w >> 2;
            f32x4 ac0 = {0,0,0,0}, ac1 = {0,0,0,0};
#pragma unroll
            for (int kk = 0; kk < 2; ++kk) {
                short8 av = *(const short8*)&tb[(m * 16 + ln) * 72 + kk * 32 + lh * 8];
                short8 b0 = *(const short8*)&hbT[(n0 * 16 + ln) * 72 + kk * 32 + lh * 8];
                short8 b1 = *(const short8*)&hbT[((n0 + 2) * 16 + ln) * 72 + kk * 32 + lh * 8];
                ac0 = MFMA16(av, b0, ac0);
                ac1 = MFMA16(av, b1, ac1);
            }
#pragma unroll
            for (int q = 0; q < 4; ++q) {
                const int row = m * 16 + lh * 4 + q;
                const int c0 = n0 * 16 + ln;
                h32[row * 67 + c0]      = ac0[q];
                h32[row * 67 + c0 + 32] = ac1[q];
                hb[row * 72 + c0]       = f2bf(ac0[q]);
                hb[row * 72 + c0 + 32]  = f2bf(ac1[q]);
            }
        }
        __syncthreads();

        // ===== phase 9: predictor on post-BTP h (t < T-1) =====
        if (t < T_STEPS - 1) {
            const int c = tid >> 3, jj = tid & 7;
            float p = 0.f;
#pragma unroll
            for (int u = 0; u < 8; ++u) p = fmaf(h32[c * 67 + jj * 8 + u], pw_s[jj * 8 + u], p);
            p += __shfl_xor(p, 1); p += __shfl_xor(p, 2); p += __shfl_xor(p, 4);
            if (jj == 0) predicted[((size_t)b * (T_STEPS - 1) + t) * 64 + c] = p + pbv;
        }
        // next phase-1 reads hb (barrier above); h32 next written after phase-1 barrier
    }
}

// ---------------- copy x[:,1:,:] ----------------------------------------------------------
__global__ void copyx_kernel(const float* __restrict__ x, float* __restrict__ out5)
{
    int i = blockIdx.x * 256 + threadIdx.x;
    if (i < B_BATCH * (T_STEPS - 1) * C_COMP) {
        int b = i / ((T_STEPS - 1) * C_COMP);
        int r = i - b * (T_STEPS - 1) * C_COMP;
        out5[i] = x[(size_t)b * (T_STEPS * C_COMP) + r + C_COMP];
    }
}

// ---------------- fp32 tiled GEMM: C = act(A[M,K] @ B[N,K]^T + bias) ----------------------
__global__ __launch_bounds__(256) void gemm_bias_act(
    const float* __restrict__ A, const float* __restrict__ Bw,
    const float* __restrict__ bias, float* __restrict__ Cout,
    int M, int N, int K, int relu)
{
    __shared__ __align__(16) float As[16 * 132];
    __shared__ __align__(16) float Bs[16 * 132];
    const int tid = threadIdx.x;
    const int m0 = blockIdx.x * 128, n0 = blockIdx.y * 128;
    const int tr = tid >> 4, tc = tid & 15;
    const int lrow = tid >> 1;
    const int lk = (tid & 1) * 8;

    float acc[8][8];
#pragma unroll
    for (int i = 0; i < 8; ++i)
#pragma unroll
        for (int j = 0; j < 8; ++j) acc[i][j] = 0.f;

    for (int k0 = 0; k0 < K; k0 += 16) {
        float4 a0 = *reinterpret_cast<const float4*>(&A[(size_t)(m0 + lrow) * K + k0 + lk]);
        float4 a1 = *reinterpret_cast<const float4*>(&A[(size_t)(m0 + lrow) * K + k0 + lk + 4]);
        float4 b0 = *reinterpret_cast<const float4*>(&Bw[(size_t)(n0 + lrow) * K + k0 + lk]);
        float4 b1 = *reinterpret_cast<const float4*>(&Bw[(size_t)(n0 + lrow) * K + k0 + lk + 4]);
        __syncthreads();
        As[(lk + 0) * 132 + lrow] = a0.x; As[(lk + 1) * 132 + lrow] = a0.y;
        As[(lk + 2) * 132 + lrow] = a0.z; As[(lk + 3) * 132 + lrow] = a0.w;
        As[(lk + 4) * 132 + lrow] = a1.x; As[(lk + 5) * 132 + lrow] = a1.y;
        As[(lk + 6) * 132 + lrow] = a1.z; As[(lk + 7) * 132 + lrow] = a1.w;
        Bs[(lk + 0) * 132 + lrow] = b0.x; Bs[(lk + 1) * 132 + lrow] = b0.y;
        Bs[(lk + 2) * 132 + lrow] = b0.z; Bs[(lk + 3) * 132 + lrow] = b0.w;
        Bs[(lk + 4) * 132 + lrow] = b1.x; Bs[(lk + 5) * 132 + lrow] = b1.y;
        Bs[(lk + 6) * 132 + lrow] = b1.z; Bs[(lk + 7) * 132 + lrow] = b1.w;
        __syncthreads();
#pragma unroll
        for (int kk = 0; kk < 16; ++kk) {
            float av[8], bv[8];
            float4 t0 = *reinterpret_cast<const float4*>(&As[kk * 132 + tr * 8]);
            float4 t1 = *reinterpret_cast<const float4*>(&As[kk * 132 + tr * 8 + 4]);
            av[0]=t0.x; av[1]=t0.y; av[2]=t0.z; av[3]=t0.w; av[4]=t1.x; av[5]=t1.y; av[6]=t1.z; av[7]=t1.w;
            float4 u0 = *reinterpret_cast<const float4*>(&Bs[kk * 132 + tc * 8]);
            float4 u1 = *reinterpret_cast<const float4*>(&Bs[kk * 132 + tc * 8 + 4]);
            bv[0]=u0.x; bv[1]=u0.y; bv[2]=u0.z; bv[3]=u0.w; bv[4]=u1.x; bv[5]=u1.y; bv[6]=u1.z; bv[7]=u1.w;
#pragma unroll
            for (int i = 0; i < 8; ++i)
#pragma unroll
                for (int j = 0; j < 8; ++j) acc[i][j] = fmaf(av[i], bv[j], acc[i][j]);
        }
    }
#pragma unroll
    for (int i = 0; i < 8; ++i) {
        const int cm = m0 + tr * 8 + i;
#pragma unroll
        for (int j = 0; j < 8; ++j) {
            const int cn = n0 + tc * 8 + j;
            float v = acc[i][j] + bias[cn];
            if (relu) v = fmaxf(v, 0.f);
            Cout[(size_t)cm * N + cn] = v;
        }
    }
}

__global__ __launch_bounds__(256) void clf3_kernel(const float* __restrict__ h2,
    const float* __restrict__ w3, const float* __restrict__ b3,
    float* __restrict__ TL, int m0, int Mchunk)
{
    const int lane = threadIdx.x & 63;
    const int w = threadIdx.x >> 6;
    const int r = blockIdx.x * 4 + w;
    if (r >= Mchunk) return;
    const float* hr = h2 + (size_t)r * 1024;
    float a0 = 0.f, a1 = 0.f;
    for (int i = 0; i < 16; ++i) {
        const int k = lane + i * 64;
        const float hv = hr[k];
        a0 = fmaf(hv, w3[k], a0);
        a1 = fmaf(hv, w3[1024 + k], a1);
    }
    for (int off = 32; off; off >>= 1) { a0 += __shfl_xor(a0, off); a1 += __shfl_xor(a1, off); }
    if (lane == 0) {
        const size_t row = (size_t)m0 + r;
        TL[row * 2 + 0] = a0 + b3[0];
        TL[row * 2 + 1] = a1 + b3[1];
    }
}

__global__ void logits_kernel(const float* __restrict__ TL, float* __restrict__ out)
{
    const int tid = threadIdx.x;
    if (tid >= 128) return;
    const int b = tid >> 1, o = tid & 1;
    float s = 0.f;
    for (int t = 0; t < T_STEPS; ++t) s += TL[((size_t)b * T_STEPS + t) * 2 + o];
    out[b * 2 + o] = s * (1.0f / 256.0f);
}

extern "C" void kernel_launch(void* const* d_in, const int* in_sizes, int n_in,
                              void* d_out, int out_size, void* d_ws, size_t ws_size,
                              hipStream_t stream)
{
    const float* x       = (const float*)d_in[0];
    const float* embed_w = (const float*)d_in[1];
    const float* embed_b = (const float*)d_in[2];
    const float* w_ih    = (const float*)d_in[3];
    const float* w_hh    = (const float*)d_in[4];
    const float* b_ih    = (const float*)d_in[5];
    const float* b_hh    = (const float*)d_in[6];
    const float* q1w = (const float*)d_in[7],  *q1b = (const float*)d_in[8];
    const float* q2w = (const float*)d_in[9],  *q2b = (const float*)d_in[10];
    const float* q3w = (const float*)d_in[11], *q3b = (const float*)d_in[12];
    const float* k1w = (const float*)d_in[13], *k1b = (const float*)d_in[14];
    const float* k2w = (const float*)d_in[15], *k2b = (const float*)d_in[16];
    const float* k3w = (const float*)d_in[17], *k3b = (const float*)d_in[18];
    const float* gate_bias = (const float*)d_in[19];
    const float* c1w = (const float*)d_in[20], *c1b = (const float*)d_in[21];
    const float* c2w = (const float*)d_in[22], *c2b = (const float*)d_in[23];
    const float* c3w = (const float*)d_in[24], *c3b = (const float*)d_in[25];
    const float* pw  = (const float*)d_in[26], *pb  = (const float*)d_in[27];

    float* out       = (float*)d_out;
    float* logits    = out;
    float* matrices  = out + MAT_OFF;
    float* TL        = out + TL_OFF;
    float* predicted = out + PRED_OFF;
    float* xcopy     = out + XC_OFF;

    float* ws   = (float*)d_ws;
    float* avec = ws;
    float* cvec = ws + 192;
    short* wsw  = (short*)((char*)d_ws + WSW_BYTE_OFF);
    float* h1   = ws + CLF_F32_OFF;

    size_t avail = (ws_size / 4 > CLF_F32_OFF) ? ws_size / 4 - CLF_F32_OFF : 0;
    int R = 16384;
    while (R > 128 && (size_t)R * 3072 > avail) R >>= 1;
    float* h2 = h1 + (size_t)R * 2048;

    precompute_kernel<<<1, 256, 0, stream>>>(w_ih, embed_w, embed_b, b_ih, avec, cvec);

    tobf16_kernel<<<(12288 + 255) / 256, 256, 0, stream>>>(w_hh, wsw + WHH_OFF, 12288);
    tobf16_kernel<<<(8192  + 255) / 256, 256, 0, stream>>>(q1w,  wsw + Q1_OFF,  8192);
    tobf16_kernel<<<(8192  + 255) / 256, 256, 0, stream>>>(k1w,  wsw + K1_OFF,  8192);
    tobf16_kernel<<<(16384 + 255) / 256, 256, 0, stream>>>(q2w,  wsw + Q2_OFF,  16384);
    tobf16_kernel<<<(16384 + 255) / 256, 256, 0, stream>>>(k2w,  wsw + K2_OFF,  16384);
    tobf16_kernel<<<(16384 + 255) / 256, 256, 0, stream>>>(q3w,  wsw + Q3_OFF,  16384);
    tobf16_kernel<<<(16384 + 255) / 256, 256, 0, stream>>>(k3w,  wsw + K3_OFF,  16384);

    scan_kernel<<<B_BATCH, 512, 0, stream>>>(x, b_hh, avec, cvec, wsw,
        q1b, q2b, q3b, k1b, k2b, k3b, gate_bias, pw, pb, matrices, predicted);

    copyx_kernel<<<(B_BATCH * (T_STEPS - 1) * C_COMP + 255) / 256, 256, 0, stream>>>(x, xcopy);

    const int Mtot = B_BATCH * T_STEPS;   // 16384
    for (int m0 = 0; m0 < Mtot; m0 += R) {
        gemm_bias_act<<<dim3(R / 128, 2048 / 128), 256, 0, stream>>>(
            matrices + (size_t)m0 * 4096, c1w, c1b, h1, R, 2048, 4096, 1);
        gemm_bias_act<<<dim3(R / 128, 1024 / 128), 256, 0, stream>>>(
            h1, c2w, c2b, h2, R, 1024, 2048, 1);
        clf3_kernel<<<R / 4, 256, 0, stream>>>(h2, c3w, c3b, TL, m0, R);
    }
    logits_kernel<<<1, 128, 0, stream>>>(TL, logits);
}

// Round 3
// 3262.050 us; speedup vs baseline: 53.7813x; 2.1132x over previous
//
#include <hip/hip_runtime.h>
#include <math.h>

#define B_BATCH 64
#define T_STEPS 256
#define C_COMP  64

// ws layout: floats [0..191] avec, [192..383] cvec; byte 2048+ : scan bf16 weights
#define WSW_BYTE_OFF 2048
#define WHH_OFF 0
#define Q1_OFF 12288
#define K1_OFF 20480
#define Q2_OFF 28672
#define K2_OFF 45056
#define Q3_OFF 61440
#define K3_OFF 77824
// classifier scratch (bytes)
#define C1WB_BYTE 262144
#define C2WB_BYTE 17039360
#define H1B_BYTE  21233664
#define H2B_BYTE  88342528

// output offsets (floats)
#define MAT_OFF  128
#define TL_OFF   67108992
#define PRED_OFF 67141760
#define XC_OFF   68186240

typedef __attribute__((ext_vector_type(8))) short short8;
typedef __attribute__((ext_vector_type(4))) float f32x4;
#define MFMA16(a,b,c) __builtin_amdgcn_mfma_f32_16x16x32_bf16(a,b,c,0,0,0)

__device__ __forceinline__ float sigm(float v) { return 1.0f / (1.0f + expf(-v)); }
__device__ __forceinline__ float tanh_f(float v) {
    float e = expf(2.0f * v);
    return 1.0f - 2.0f / (e + 1.0f);
}
__device__ __forceinline__ short f2bf(float f) {  // RNE f32->bf16 bits
    unsigned u = __float_as_uint(f);
    u += 0x7fffu + ((u >> 16) & 1u);
    return (short)(u >> 16);
}
__device__ __forceinline__ float bf2f(short s) {
    return __uint_as_float(((unsigned)(unsigned short)s) << 16);
}
__device__ __forceinline__ void async16(void* lds, const void* g) {
    __builtin_amdgcn_global_load_lds((const __attribute__((address_space(1))) void*)g,
                                     (__attribute__((address_space(3))) void*)lds, 16, 0, 0);
}

// ---------------- precompute rank-1 embedding+input path --------------------------------
__global__ void precompute_kernel(const float* __restrict__ w_ih,
                                  const float* __restrict__ embed_w,
                                  const float* __restrict__ embed_b,
                                  const float* __restrict__ b_ih,
                                  float* __restrict__ avec, float* __restrict__ cvec)
{
    int g = threadIdx.x;
    if (g < 192) {
        float a = 0.f, c = 0.f;
        for (int e = 0; e < 32; ++e) {
            float w = w_ih[g * 32 + e];
            a += w * embed_w[e];
            c += w * embed_b[e];
        }
        avec[g] = a;
        cvec[g] = c + b_ih[g];
    }
}

__global__ void tobf16_kernel(const float* __restrict__ src, short* __restrict__ dst, int n)
{
    int i = blockIdx.x * 256 + threadIdx.x;
    if (i < n) dst[i] = f2bf(src[i]);
}

// one MLP layer: this wave computes 2 column-strips of out[64][*], all 4 m-tiles.
template<int KST, bool RELU>
__device__ __forceinline__ void two_strip_layer(
    const short* __restrict__ A, const int ast,
    const short8* __restrict__ Bs0, const short8* __restrict__ Bs1,
    const float bias0, const float bias1,
    short* __restrict__ outb, const int ost,
    const int s0, const int s1, const int ln, const int lh)
{
    f32x4 acc0[4], acc1[4];
#pragma unroll
    for (int m = 0; m < 4; ++m) {
        acc0[m] = (f32x4){bias0, bias0, bias0, bias0};
        acc1[m] = (f32x4){bias1, bias1, bias1, bias1};
    }
#pragma unroll
    for (int kk = 0; kk < KST; ++kk) {
#pragma unroll
        for (int m = 0; m < 4; ++m) {
            short8 a = *(const short8*)&A[(m * 16 + ln) * ast + kk * 32 + lh * 8];
            acc0[m] = MFMA16(a, Bs0[kk], acc0[m]);
            acc1[m] = MFMA16(a, Bs1[kk], acc1[m]);
        }
    }
#pragma unroll
    for (int m = 0; m < 4; ++m) {
#pragma unroll
        for (int q = 0; q < 4; ++q) {
            const int row = m * 16 + lh * 4 + q;
            float v0 = acc0[m][q], v1 = acc1[m][q];
            if (RELU) { v0 = fmaxf(v0, 0.f); v1 = fmaxf(v1, 0.f); }
            outb[row * ost + s0 * 16 + ln] = f2bf(v0);
            outb[row * ost + s1 * 16 + ln] = f2bf(v1);
        }
    }
}

// ---------------- the scan: one block (8 waves) per batch, MFMA everywhere ---------------
__global__ __launch_bounds__(512) void scan_kernel(
    const float* __restrict__ x, const float* __restrict__ b_hh,
    const float* __restrict__ avec, const float* __restrict__ cvec,
    const short* __restrict__ wsw,
    const float* __restrict__ q1b, const float* __restrict__ q2b, const float* __restrict__ q3b,
    const float* __restrict__ k1b, const float* __restrict__ k2b, const float* __restrict__ k3b,
    const float* __restrict__ gate_bias,
    const float* __restrict__ pred_w, const float* __restrict__ pred_b,
    float* __restrict__ matrices, float* __restrict__ predicted)
{
    __shared__ __align__(16) float h32[64 * 67];
    __shared__ __align__(16) short hb [64 * 72];
    __shared__ __align__(16) short hbT[64 * 72];
    __shared__ __align__(16) short qf [64 * 136];
    __shared__ __align__(16) short kf [64 * 136];
    __shared__ __align__(16) char scratch[69632];
    __shared__ float avec_s[192], cvec_s[192], bhh_s[192], pw_s[64], xrow[64], red[8];

    float* gates = (float*)scratch;                 // [64][193] f32
    short* act1q = (short*)scratch;                 // [64][136] bf16
    short* act1k = (short*)(scratch + 17408);
    short* act2q = (short*)(scratch + 34816);
    short* act2k = (short*)(scratch + 52224);
    float* tf    = (float*)scratch;                 // [64][67] f32
    short* tb    = (short*)(scratch + 17408);       // [64][72] bf16

    const int tid = threadIdx.x;
    const int b = blockIdx.x;
    const int w = tid >> 6, lane = tid & 63;
    const int ln = lane & 15, lh = lane >> 4;
    const int wq = w & 3;

    for (int i = tid; i < 64 * 67; i += 512) h32[i] = 0.f;
    for (int i = tid; i < 64 * 72; i += 512) hb[i] = 0;
    if (tid < 192) { avec_s[tid] = avec[tid]; cvec_s[tid] = cvec[tid]; bhh_s[tid] = b_hh[tid]; }
    if (tid < 64) pw_s[tid] = pred_w[tid];
    const float pbv = pred_b[0];

    const short* whh_b = wsw + WHH_OFF;
    const short* l1w = (w < 4) ? wsw + Q1_OFF : wsw + K1_OFF;
    const short* l2w = (w < 4) ? wsw + Q2_OFF : wsw + K2_OFF;
    const short* l3w = (w < 4) ? wsw + Q3_OFF : wsw + K3_OFF;
    const float* l1b = (w < 4) ? q1b : k1b;
    const float* l2b = (w < 4) ? q2b : k2b;
    const float* l3b = (w < 4) ? q3b : k3b;

    short8 Bg[2][2], B1[2][2], B2[2][4], B3[2][4];
    {
        const int sg1 = (w < 4) ? (w + 8) : w;
#pragma unroll
        for (int kk = 0; kk < 2; ++kk) {
            Bg[0][kk] = *(const short8*)&whh_b[(w   * 16 + ln) * 64 + kk * 32 + lh * 8];
            Bg[1][kk] = *(const short8*)&whh_b[(sg1 * 16 + ln) * 64 + kk * 32 + lh * 8];
        }
#pragma unroll
        for (int s = 0; s < 2; ++s) {
            const int strip = wq + s * 4;
#pragma unroll
            for (int kk = 0; kk < 2; ++kk)
                B1[s][kk] = *(const short8*)&l1w[(strip * 16 + ln) * 64 + kk * 32 + lh * 8];
#pragma unroll
            for (int kk = 0; kk < 4; ++kk) {
                B2[s][kk] = *(const short8*)&l2w[(strip * 16 + ln) * 128 + kk * 32 + lh * 8];
                B3[s][kk] = *(const short8*)&l3w[(strip * 16 + ln) * 128 + kk * 32 + lh * 8];
            }
        }
    }
    const float b1v0 = l1b[wq * 16 + ln],       b1v1 = l1b[(wq + 4) * 16 + ln];
    const float b2v0 = l2b[wq * 16 + ln],       b2v1 = l2b[(wq + 4) * 16 + ln];
    const float b3v0 = l3b[wq * 16 + ln],       b3v1 = l3b[(wq + 4) * 16 + ln];
    __syncthreads();

    for (int t = 0; t < T_STEPS; ++t) {
        // ===== phase 1: gh = hb @ w_hh^T =====
        {
            f32x4 a0[4], a1[4];
#pragma unroll
            for (int m = 0; m < 4; ++m) { a0[m] = (f32x4){0,0,0,0}; a1[m] = (f32x4){0,0,0,0}; }
#pragma unroll
            for (int kk = 0; kk < 2; ++kk)
#pragma unroll
                for (int m = 0; m < 4; ++m) {
                    short8 av = *(const short8*)&hb[(m * 16 + ln) * 72 + kk * 32 + lh * 8];
                    a0[m] = MFMA16(av, Bg[0][kk], a0[m]);
                    a1[m] = MFMA16(av, Bg[1][kk], a1[m]);
                }
#pragma unroll
            for (int m = 0; m < 4; ++m)
#pragma unroll
                for (int q = 0; q < 4; ++q)
                    gates[(m * 16 + lh * 4 + q) * 193 + w * 16 + ln] = a0[m][q];
            if (w < 4) {
#pragma unroll
                for (int m = 0; m < 4; ++m)
#pragma unroll
                    for (int q = 0; q < 4; ++q)
                        gates[(m * 16 + lh * 4 + q) * 193 + (w + 8) * 16 + ln] = a1[m][q];
            }
        }
        if (tid < 64) xrow[tid] = x[((size_t)b * T_STEPS + t) * 64 + tid];
        __syncthreads();

        // ===== phase 2: GRU elementwise =====
        {
            const int c = tid >> 3, j0 = (tid & 7) * 8;
            const float xv = xrow[c];
#pragma unroll
            for (int jj = 0; jj < 8; ++jj) {
                const int j = j0 + jj;
                const float ghr = gates[c * 193 + j]       + bhh_s[j];
                const float ghz = gates[c * 193 + 64 + j]  + bhh_s[64 + j];
                const float ghn = gates[c * 193 + 128 + j] + bhh_s[128 + j];
                const float r = sigm(fmaf(xv, avec_s[j],        cvec_s[j])        + ghr);
                const float z = sigm(fmaf(xv, avec_s[64 + j],   cvec_s[64 + j])   + ghz);
                const float n = tanh_f(fmaf(xv, avec_s[128 + j], cvec_s[128 + j]) + r * ghn);
                const float hold = h32[c * 67 + j];
                const float hn = fmaf(z, hold - n, n);
                h32[c * 67 + j] = hn;
                const short hv = f2bf(hn);
                hb[c * 72 + j] = hv;
                hbT[j * 72 + c] = hv;
            }
        }
        __syncthreads();

        // ===== phases 3-5: q / k MLPs =====
        short* o1 = (w < 4) ? act1q : act1k;
        two_strip_layer<2, true >(hb, 72, B1[0], B1[1], b1v0, b1v1, o1, 136, wq, wq + 4, ln, lh);
        __syncthreads();
        short* o2 = (w < 4) ? act2q : act2k;
        two_strip_layer<4, true >(o1, 136, B2[0], B2[1], b2v0, b2v1, o2, 136, wq, wq + 4, ln, lh);
        __syncthreads();
        short* o3 = (w < 4) ? qf : kf;
        two_strip_layer<4, false>(o2, 136, B3[0], B3[1], b3v0, b3v1, o3, 136, wq, wq + 4, ln, lh);
        __syncthreads();

        // ===== phase 6: transfer = qf @ kf^T =====
        {
            const int m = wq, n0 = w >> 2;
            f32x4 ac0 = {0,0,0,0}, ac1 = {0,0,0,0};
#pragma unroll
            for (int kk = 0; kk < 4; ++kk) {
                short8 av = *(const short8*)&qf[(m * 16 + ln) * 136 + kk * 32 + lh * 8];
                short8 b0 = *(const short8*)&kf[(n0 * 16 + ln) * 136 + kk * 32 + lh * 8];
                short8 b1 = *(const short8*)&kf[((n0 + 2) * 16 + ln) * 136 + kk * 32 + lh * 8];
                ac0 = MFMA16(av, b0, ac0);
                ac1 = MFMA16(av, b1, ac1);
            }
            float ss = 0.f;
#pragma unroll
            for (int q = 0; q < 4; ++q) {
                const int row = m * 16 + lh * 4 + q;
                tf[row * 67 + n0 * 16 + ln] = ac0[q];
                tf[row * 67 + (n0 + 2) * 16 + ln] = ac1[q];
                ss = fmaf(ac0[q], ac0[q], fmaf(ac1[q], ac1[q], ss));
            }
#pragma unroll
            for (int off = 1; off < 64; off <<= 1) ss += __shfl_xor(ss, off);
            if (lane == 0) red[w] = ss;
        }
        __syncthreads();

        // ===== phase 7: normalize + gate -> matrices + tb =====
        {
            const float ssum = red[0]+red[1]+red[2]+red[3]+red[4]+red[5]+red[6]+red[7];
            const float inv = 1.0f / sqrtf(ssum);
            const size_t mbase = ((size_t)b * T_STEPS + t) * 4096;
#pragma unroll
            for (int it = 0; it < 8; ++it) {
                const int e = it * 512 + tid;
                const int ci = e >> 6, cj = e & 63;
                const float tv = tf[ci * 67 + cj] * inv;
                const float g = sigm(fabsf(tv) + gate_bias[e]);
                const float val = tv * g;
                matrices[mbase + e] = val;
                tb[ci * 72 + cj] = f2bf(val);
            }
        }
        __syncthreads();

        // ===== phase 8: h = tb @ h_postGRU =====
        {
            const int m = wq, n0 = w >> 2;
            f32x4 ac0 = {0,0,0,0}, ac1 = {0,0,0,0};
#pragma unroll
            for (int kk = 0; kk < 2; ++kk) {
                short8 av = *(const short8*)&tb[(m * 16 + ln) * 72 + kk * 32 + lh * 8];
                short8 b0 = *(const short8*)&hbT[(n0 * 16 + ln) * 72 + kk * 32 + lh * 8];
                short8 b1 = *(const short8*)&hbT[((n0 + 2) * 16 + ln) * 72 + kk * 32 + lh * 8];
                ac0 = MFMA16(av, b0, ac0);
                ac1 = MFMA16(av, b1, ac1);
            }
#pragma unroll
            for (int q = 0; q < 4; ++q) {
                const int row = m * 16 + lh * 4 + q;
                const int c0 = n0 * 16 + ln;
                h32[row * 67 + c0]      = ac0[q];
                h32[row * 67 + c0 + 32] = ac1[q];
                hb[row * 72 + c0]       = f2bf(ac0[q]);
                hb[row * 72 + c0 + 32]  = f2bf(ac1[q]);
            }
        }
        __syncthreads();

        // ===== phase 9: predictor =====
        if (t < T_STEPS - 1) {
            const int c = tid >> 3, jj = tid & 7;
            float p = 0.f;
#pragma unroll
            for (int u = 0; u < 8; ++u) p = fmaf(h32[c * 67 + jj * 8 + u], pw_s[jj * 8 + u], p);
            p += __shfl_xor(p, 1); p += __shfl_xor(p, 2); p += __shfl_xor(p, 4);
            if (jj == 0) predicted[((size_t)b * (T_STEPS - 1) + t) * 64 + c] = p + pbv;
        }
    }
}

// ---------------- copy x[:,1:,:] ----------------------------------------------------------
__global__ void copyx_kernel(const float* __restrict__ x, float* __restrict__ out5)
{
    int i = blockIdx.x * 256 + threadIdx.x;
    if (i < B_BATCH * (T_STEPS - 1) * C_COMP) {
        int b = i / ((T_STEPS - 1) * C_COMP);
        int r = i - b * (T_STEPS - 1) * C_COMP;
        out5[i] = x[(size_t)b * (T_STEPS * C_COMP) + r + C_COMP];
    }
}

// ---------------- clf1: A fp32 (reg-convert) x B bf16 (gload_lds) -> bf16 C ---------------
// 128x128 tile, BK=64, 4 waves. XCD-swizzled linear grid: same A-panel -> same XCD.
__global__ __launch_bounds__(256) void gemm1_kernel(
    const float* __restrict__ A, const short* __restrict__ Bw,
    const float* __restrict__ bias, short* __restrict__ Cb,
    const int M, const int N, const int K)
{
    __shared__ __align__(16) short Asb[128 * 64];
    __shared__ __align__(16) short Bsb[128 * 64];
    const int tid = threadIdx.x;
    const int w = tid >> 6, lane = tid & 63;
    const int ln = lane & 15, lh = lane >> 4;
    const int wr = w >> 1, wc = w & 1;

    const int ntc = N >> 7;
    const int g = blockIdx.x;
    const int xcd = g & 7, chunk = g >> 3;
    const int mt = xcd * ((M >> 7) >> 3) + chunk / ntc;
    const int nt = chunk % ntc;
    const int m0 = mt << 7, n0 = nt << 7;

    const int ar = tid >> 1;
    const int ac = (tid & 1) << 5;
    const short* bsrc = Bw + (size_t)(n0 + w * 32 + (lane >> 3)) * K + ((lane & 7) << 3);
    short* bdst = &Bsb[w * 32 * 64 + lane * 8];

    f32x4 acc[4][4];
#pragma unroll
    for (int m = 0; m < 4; ++m)
#pragma unroll
        for (int n = 0; n < 4; ++n) acc[m][n] = (f32x4){0, 0, 0, 0};

    for (int k0 = 0; k0 < K; k0 += 64) {
        const float* arow = A + (size_t)(m0 + ar) * K + k0 + ac;
        float4 av[8];
#pragma unroll
        for (int i = 0; i < 8; ++i) av[i] = *reinterpret_cast<const float4*>(arow + i * 4);
        short8 cv[4];
#pragma unroll
        for (int i = 0; i < 4; ++i) {
            cv[i][0] = f2bf(av[2*i].x);   cv[i][1] = f2bf(av[2*i].y);
            cv[i][2] = f2bf(av[2*i].z);   cv[i][3] = f2bf(av[2*i].w);
            cv[i][4] = f2bf(av[2*i+1].x); cv[i][5] = f2bf(av[2*i+1].y);
            cv[i][6] = f2bf(av[2*i+1].z); cv[i][7] = f2bf(av[2*i+1].w);
        }
        __syncthreads();   // prev compute done
#pragma unroll
        for (int i = 0; i < 4; ++i)
            *reinterpret_cast<short8*>(&Asb[ar * 64 + ac + i * 8]) = cv[i];
#pragma unroll
        for (int i = 0; i < 4; ++i)
            async16(bdst + i * 512, bsrc + (size_t)i * 8 * K + k0);
        __syncthreads();   // drain staging
#pragma unroll
        for (int kk = 0; kk < 2; ++kk) {
            short8 af[4], bfr[4];
#pragma unroll
            for (int m = 0; m < 4; ++m)
                af[m] = *reinterpret_cast<const short8*>(&Asb[(wr*64 + m*16 + ln)*64 + kk*32 + lh*8]);
#pragma unroll
            for (int n = 0; n < 4; ++n)
                bfr[n] = *reinterpret_cast<const short8*>(&Bsb[(wc*64 + n*16 + ln)*64 + kk*32 + lh*8]);
#pragma unroll
            for (int m = 0; m < 4; ++m)
#pragma unroll
                for (int n = 0; n < 4; ++n)
                    acc[m][n] = MFMA16(af[m], bfr[n], acc[m][n]);
        }
    }
#pragma unroll
    for (int n = 0; n < 4; ++n) {
        const int col = n0 + wc * 64 + n * 16 + ln;
        const float bv = bias[col];
#pragma unroll
        for (int m = 0; m < 4; ++m)
#pragma unroll
            for (int q = 0; q < 4; ++q) {
                const int row = m0 + wr * 64 + m * 16 + lh * 4 + q;
                Cb[(size_t)row * N + col] = f2bf(fmaxf(acc[m][n][q] + bv, 0.f));
            }
    }
}

// ---------------- clf2: both operands bf16 via gload_lds ----------------------------------
__global__ __launch_bounds__(256) void gemm2_kernel(
    const short* __restrict__ Ab, const short* __restrict__ Bw,
    const float* __restrict__ bias, short* __restrict__ Cb,
    const int M, const int N, const int K)
{
    __shared__ __align__(16) short Asb[128 * 64];
    __shared__ __align__(16) short Bsb[128 * 64];
    const int tid = threadIdx.x;
    const int w = tid >> 6, lane = tid & 63;
    const int ln = lane & 15, lh = lane >> 4;
    const int wr = w >> 1, wc = w & 1;

    const int ntc = N >> 7;
    const int g = blockIdx.x;
    const int xcd = g & 7, chunk = g >> 3;
    const int mt = xcd * ((M >> 7) >> 3) + chunk / ntc;
    const int nt = chunk % ntc;
    const int m0 = mt << 7, n0 = nt << 7;

    const short* asrc = Ab + (size_t)(m0 + w * 32 + (lane >> 3)) * K + ((lane & 7) << 3);
    const short* bsrc = Bw + (size_t)(n0 + w * 32 + (lane >> 3)) * K + ((lane & 7) << 3);
    short* adst = &Asb[w * 32 * 64 + lane * 8];
    short* bdst = &Bsb[w * 32 * 64 + lane * 8];

    f32x4 acc[4][4];
#pragma unroll
    for (int m = 0; m < 4; ++m)
#pragma unroll
        for (int n = 0; n < 4; ++n) acc[m][n] = (f32x4){0, 0, 0, 0};

    for (int k0 = 0; k0 < K; k0 += 64) {
        __syncthreads();
#pragma unroll
        for (int i = 0; i < 4; ++i) {
            async16(adst + i * 512, asrc + (size_t)i * 8 * K + k0);
            async16(bdst + i * 512, bsrc + (size_t)i * 8 * K + k0);
        }
        __syncthreads();
#pragma unroll
        for (int kk = 0; kk < 2; ++kk) {
            short8 af[4], bfr[4];
#pragma unroll
            for (int m = 0; m < 4; ++m)
                af[m] = *reinterpret_cast<const short8*>(&Asb[(wr*64 + m*16 + ln)*64 + kk*32 + lh*8]);
#pragma unroll
            for (int n = 0; n < 4; ++n)
                bfr[n] = *reinterpret_cast<const short8*>(&Bsb[(wc*64 + n*16 + ln)*64 + kk*32 + lh*8]);
#pragma unroll
            for (int m = 0; m < 4; ++m)
#pragma unroll
                for (int n = 0; n < 4; ++n)
                    acc[m][n] = MFMA16(af[m], bfr[n], acc[m][n]);
        }
    }
#pragma unroll
    for (int n = 0; n < 4; ++n) {
        const int col = n0 + wc * 64 + n * 16 + ln;
        const float bv = bias[col];
#pragma unroll
        for (int m = 0; m < 4; ++m)
#pragma unroll
            for (int q = 0; q < 4; ++q) {
                const int row = m0 + wr * 64 + m * 16 + lh * 4 + q;
                Cb[(size_t)row * N + col] = f2bf(fmaxf(acc[m][n][q] + bv, 0.f));
            }
    }
}

// ---------------- clf3: [M,1024] bf16 -> time_logits [M,2] --------------------------------
__global__ __launch_bounds__(256) void clf3_kernel(const short* __restrict__ h2b,
    const float* __restrict__ w3, const float* __restrict__ b3, float* __restrict__ TL)
{
    const int lane = threadIdx.x & 63;
    const int w = threadIdx.x >> 6;
    const size_t r = (size_t)blockIdx.x * 4 + w;
    const short* hr = h2b + r * 1024;
    float a0 = 0.f, a1 = 0.f;
#pragma unroll
    for (int half = 0; half < 2; ++half) {
        const int k = half * 512 + lane * 8;
        short8 hv = *(const short8*)&hr[k];
#pragma unroll
        for (int u = 0; u < 8; ++u) {
            const float hf = bf2f(hv[u]);
            a0 = fmaf(hf, w3[k + u], a0);
            a1 = fmaf(hf, w3[1024 + k + u], a1);
        }
    }
    for (int off = 32; off; off >>= 1) { a0 += __shfl_xor(a0, off); a1 += __shfl_xor(a1, off); }
    if (lane == 0) {
        TL[r * 2 + 0] = a0 + b3[0];
        TL[r * 2 + 1] = a1 + b3[1];
    }
}

__global__ void logits_kernel(const float* __restrict__ TL, float* __restrict__ out)
{
    const int tid = threadIdx.x;
    if (tid >= 128) return;
    const int b = tid >> 1, o = tid & 1;
    float s = 0.f;
    for (int t = 0; t < T_STEPS; ++t) s += TL[((size_t)b * T_STEPS + t) * 2 + o];
    out[b * 2 + o] = s * (1.0f / 256.0f);
}

extern "C" void kernel_launch(void* const* d_in, const int* in_sizes, int n_in,
                              void* d_out, int out_size, void* d_ws, size_t ws_size,
                              hipStream_t stream)
{
    const float* x       = (const float*)d_in[0];
    const float* embed_w = (const float*)d_in[1];
    const float* embed_b = (const float*)d_in[2];
    const float* w_ih    = (const float*)d_in[3];
    const float* w_hh    = (const float*)d_in[4];
    const float* b_ih    = (const float*)d_in[5];
    const float* b_hh    = (const float*)d_in[6];
    const float* q1w = (const float*)d_in[7],  *q1b = (const float*)d_in[8];
    const float* q2w = (const float*)d_in[9],  *q2b = (const float*)d_in[10];
    const float* q3w = (const float*)d_in[11], *q3b = (const float*)d_in[12];
    const float* k1w = (const float*)d_in[13], *k1b = (const float*)d_in[14];
    const float* k2w = (const float*)d_in[15], *k2b = (const float*)d_in[16];
    const float* k3w = (const float*)d_in[17], *k3b = (const float*)d_in[18];
    const float* gate_bias = (const float*)d_in[19];
    const float* c1w = (const float*)d_in[20], *c1b = (const float*)d_in[21];
    const float* c2w = (const float*)d_in[22], *c2b = (const float*)d_in[23];
    const float* c3w = (const float*)d_in[24], *c3b = (const float*)d_in[25];
    const float* pw  = (const float*)d_in[26], *pb  = (const float*)d_in[27];

    float* out       = (float*)d_out;
    float* logits    = out;
    float* matrices  = out + MAT_OFF;
    float* TL        = out + TL_OFF;
    float* predicted = out + PRED_OFF;
    float* xcopy     = out + XC_OFF;

    float* ws   = (float*)d_ws;
    float* avec = ws;
    float* cvec = ws + 192;
    short* wsw  = (short*)((char*)d_ws + WSW_BYTE_OFF);
    short* c1wb = (short*)((char*)d_ws + C1WB_BYTE);
    short* c2wb = (short*)((char*)d_ws + C2WB_BYTE);
    short* h1b  = (short*)((char*)d_ws + H1B_BYTE);
    short* h2b  = (short*)((char*)d_ws + H2B_BYTE);

    precompute_kernel<<<1, 256, 0, stream>>>(w_ih, embed_w, embed_b, b_ih, avec, cvec);

    tobf16_kernel<<<(12288 + 255) / 256, 256, 0, stream>>>(w_hh, wsw + WHH_OFF, 12288);
    tobf16_kernel<<<(8192  + 255) / 256, 256, 0, stream>>>(q1w,  wsw + Q1_OFF,  8192);
    tobf16_kernel<<<(8192  + 255) / 256, 256, 0, stream>>>(k1w,  wsw + K1_OFF,  8192);
    tobf16_kernel<<<(16384 + 255) / 256, 256, 0, stream>>>(q2w,  wsw + Q2_OFF,  16384);
    tobf16_kernel<<<(16384 + 255) / 256, 256, 0, stream>>>(k2w,  wsw + K2_OFF,  16384);
    tobf16_kernel<<<(16384 + 255) / 256, 256, 0, stream>>>(q3w,  wsw + Q3_OFF,  16384);
    tobf16_kernel<<<(16384 + 255) / 256, 256, 0, stream>>>(k3w,  wsw + K3_OFF,  16384);
    tobf16_kernel<<<(2048 * 4096 + 255) / 256, 256, 0, stream>>>(c1w, c1wb, 2048 * 4096);
    tobf16_kernel<<<(1024 * 2048 + 255) / 256, 256, 0, stream>>>(c2w, c2wb, 1024 * 2048);

    scan_kernel<<<B_BATCH, 512, 0, stream>>>(x, b_hh, avec, cvec, wsw,
        q1b, q2b, q3b, k1b, k2b, k3b, gate_bias, pw, pb, matrices, predicted);

    copyx_kernel<<<(B_BATCH * (T_STEPS - 1) * C_COMP + 255) / 256, 256, 0, stream>>>(x, xcopy);

    const int Mtot = B_BATCH * T_STEPS;   // 16384
    gemm1_kernel<<<(Mtot / 128) * (2048 / 128), 256, 0, stream>>>(
        matrices, c1wb, c1b, h1b, Mtot, 2048, 4096);
    gemm2_kernel<<<(Mtot / 128) * (1024 / 128), 256, 0, stream>>>(
        h1b, c2wb, c2b, h2b, Mtot, 1024, 2048);
    clf3_kernel<<<Mtot / 4, 256, 0, stream>>>(h2b, c3w, c3b, TL);
    logits_kernel<<<1, 128, 0, stream>>>(TL, logits);
}